// Round 2
// baseline (178.773 us; speedup 1.0000x reference)
//
#include <hip/hip_runtime.h>

// FeatureTransformerSlice: out[b, :] = bias + sum_k vals[b,k] * W[idx[b,k], :]
// B=16384, K=32, O=512, NUM_INPUTS=45056, all fp32.
//
// R2: latency-bound fix. Batch 8 independent float4 gathers into registers
// before consuming (MLP 2 -> 8 per wave). Row indices are per-block uniform:
// readfirstlane makes them SGPRs, so gather addresses are SGPR-base +
// VGPR-column-offset (no VGPR cost for addresses). Target <=64 VGPR so we
// keep the 8-waves/SIMD occupancy tier: ~256 outstanding gathers per CU.

#define B_BATCH 16384
#define K_ACT   32
#define N_OUT   512

__global__ __launch_bounds__(128, 8) void ft_slice_kernel(
    const int*   __restrict__ idx,   // [B, K]
    const float* __restrict__ val,   // [B, K]
    const float* __restrict__ W,     // [NUM_INPUTS, N_OUT]
    const float* __restrict__ bias,  // [N_OUT]
    float*       __restrict__ out)   // [B, N_OUT]
{
    const int b = blockIdx.x;
    const int t = threadIdx.x;  // 0..127, owns outputs [4t, 4t+4)
    const int col = t * 4;

    const int*   bidx = idx + b * K_ACT;
    const float* bval = val + b * K_ACT;

    float4 acc  = *reinterpret_cast<const float4*>(&bias[col]);
    float4 acc2 = make_float4(0.f, 0.f, 0.f, 0.f);

    #pragma unroll
    for (int k0 = 0; k0 < K_ACT; k0 += 8) {
        float4 w[8];
        float  v[8];
        // Issue 8 independent gathers before any consumption. Row index is
        // uniform across the block -> scalarize so the address is SGPR-based.
        #pragma unroll
        for (int j = 0; j < 8; ++j) {
            const int r = __builtin_amdgcn_readfirstlane(bidx[k0 + j]);
            v[j] = bval[k0 + j];
            w[j] = *reinterpret_cast<const float4*>(W + (size_t)r * N_OUT + col);
        }
        #pragma unroll
        for (int j = 0; j < 8; ++j) {
            if (j & 1) {
                acc2.x += v[j] * w[j].x; acc2.y += v[j] * w[j].y;
                acc2.z += v[j] * w[j].z; acc2.w += v[j] * w[j].w;
            } else {
                acc.x  += v[j] * w[j].x; acc.y  += v[j] * w[j].y;
                acc.z  += v[j] * w[j].z; acc.w  += v[j] * w[j].w;
            }
        }
    }

    acc.x += acc2.x; acc.y += acc2.y; acc.z += acc2.z; acc.w += acc2.w;
    *reinterpret_cast<float4*>(&out[(size_t)b * N_OUT + col]) = acc;
}

extern "C" void kernel_launch(void* const* d_in, const int* in_sizes, int n_in,
                              void* d_out, int out_size, void* d_ws, size_t ws_size,
                              hipStream_t stream) {
    const int*   idx  = (const int*)  d_in[0];  // feature_indices [B,K] int32
    const float* val  = (const float*)d_in[1];  // feature_values  [B,K] f32
    const float* W    = (const float*)d_in[2];  // weight [NUM_INPUTS, N_OUT] f32
    const float* bias = (const float*)d_in[3];  // bias [N_OUT] f32
    float*       out  = (float*)d_out;          // [B, N_OUT] f32

    ft_slice_kernel<<<B_BATCH, 128, 0, stream>>>(idx, val, W, bias, out);
}

// Round 3
// 151.857 us; speedup vs baseline: 1.1772x; 1.1772x over previous
//
#include <hip/hip_runtime.h>

// FeatureTransformerSlice: out[b, :] = bias + sum_k vals[b,k] * W[idx[b,k], :]
// B=16384, K=32, O=512, NUM_INPUTS=45056, all fp32.
//
// R3: latency-bound fix, done right this time.
//  - All 32 (idx,val) pairs hoisted to wave-uniform SGPRs up front:
//    lanes 0..31 load them coalesced, then readlane(const) -> SGPR.
//    Gather addresses = SGPR base + shared VGPR column offset.
//  - Software-pipelined gathers: two ping-pong float4x4 register groups,
//    4-8 loads always in flight, no full vmcnt drain inside the loop.
//  - No min-waves launch bound (R2's 64-VGPR cap caused scratch spills:
//    WRITE_SIZE 32MB -> 112MB). Target ~50 VGPR -> 8 waves/SIMD naturally.

#define B_BATCH 16384
#define K_ACT   32
#define N_OUT   512

__global__ __launch_bounds__(128) void ft_slice_kernel(
    const int*   __restrict__ idx,   // [B, K]
    const float* __restrict__ val,   // [B, K]
    const float* __restrict__ W,     // [NUM_INPUTS, N_OUT]
    const float* __restrict__ bias,  // [N_OUT]
    float*       __restrict__ out)   // [B, N_OUT]
{
    const int b = blockIdx.x;
    const int t = threadIdx.x;       // 0..127, owns outputs [4t, 4t+4)
    const int lane = t & 63;
    const int col = t * 4;

    // Lanes 0..31 of each wave load the row's (idx, val) pairs (coalesced,
    // 128B per wave); broadcast to SGPRs via readlane with constant lane id.
    int   lidx = 0;
    float lval = 0.0f;
    if (lane < K_ACT) {
        lidx = idx[b * K_ACT + lane];
        lval = val[b * K_ACT + lane];
    }

    int ridx[K_ACT];
    float rval[K_ACT];
    #pragma unroll
    for (int k = 0; k < K_ACT; ++k) {
        ridx[k] = __builtin_amdgcn_readlane(lidx, k);
        int vb  = __builtin_amdgcn_readlane(__builtin_bit_cast(int, lval), k);
        rval[k] = __builtin_bit_cast(float, vb);
    }

    float4 acc  = *reinterpret_cast<const float4*>(&bias[col]);
    float4 acc2 = make_float4(0.f, 0.f, 0.f, 0.f);

    float4 wa[4], wb[4];

    #define GATHER(dst, kbase)                                                  \
        _Pragma("unroll")                                                       \
        for (int j = 0; j < 4; ++j)                                             \
            dst[j] = *reinterpret_cast<const float4*>(                          \
                W + (size_t)ridx[(kbase) + j] * N_OUT + col);

    #define CONSUME(srcbuf, kbase)                                              \
        _Pragma("unroll")                                                       \
        for (int j = 0; j < 4; ++j) {                                           \
            const float v = rval[(kbase) + j];                                  \
            if (j & 1) {                                                        \
                acc2.x += v * srcbuf[j].x; acc2.y += v * srcbuf[j].y;           \
                acc2.z += v * srcbuf[j].z; acc2.w += v * srcbuf[j].w;           \
            } else {                                                            \
                acc.x  += v * srcbuf[j].x; acc.y  += v * srcbuf[j].y;           \
                acc.z  += v * srcbuf[j].z; acc.w  += v * srcbuf[j].w;           \
            }                                                                   \
        }

    GATHER(wa, 0);            // prefetch k = 0..3
    #pragma unroll
    for (int k0 = 0; k0 < K_ACT; k0 += 8) {
        GATHER(wb, k0 + 4);   // issue next 4 while wa in flight
        CONSUME(wa, k0);
        if (k0 + 8 < K_ACT) { GATHER(wa, k0 + 8); }
        CONSUME(wb, k0 + 4);
    }
    #undef GATHER
    #undef CONSUME

    acc.x += acc2.x; acc.y += acc2.y; acc.z += acc2.z; acc.w += acc2.w;
    *reinterpret_cast<float4*>(&out[(size_t)b * N_OUT + col]) = acc;
}

extern "C" void kernel_launch(void* const* d_in, const int* in_sizes, int n_in,
                              void* d_out, int out_size, void* d_ws, size_t ws_size,
                              hipStream_t stream) {
    const int*   idx  = (const int*)  d_in[0];  // feature_indices [B,K] int32
    const float* val  = (const float*)d_in[1];  // feature_values  [B,K] f32
    const float* W    = (const float*)d_in[2];  // weight [NUM_INPUTS, N_OUT] f32
    const float* bias = (const float*)d_in[3];  // bias [N_OUT] f32
    float*       out  = (float*)d_out;          // [B, N_OUT] f32

    ft_slice_kernel<<<B_BATCH, 128, 0, stream>>>(idx, val, W, bias, out);
}

// Round 4
// 74.228 us; speedup vs baseline: 2.4084x; 2.0458x over previous
//
#include <hip/hip_runtime.h>

// FeatureTransformerSlice: out[b,:] = bias + sum_k val[b,k] * W[idx[b,k],:]
// B=16384, K=32, O=512, NUM_INPUTS=45056, fp32.
//
// R4: the kernel is L2-miss-bandwidth bound (R1 vs R3: two different ILP
// schedules tie at 152us, FETCH pinned at 504MB ~ 3.4TB/s). Reduce miss
// bytes instead of adding MLP:
//  1. Convert W to bf16 in d_ws once per call (halves all gather bytes;
//     worst-case added error ~2.9e-4 vs 1.02e-3 threshold).
//  2. Column-partition: 8 slices of 64 cols; slice = blockIdx.x % 8 so the
//     round-robin block->XCD dispatch gives each XCD ONE slice. Per-XCD L2
//     working set: 88 MiB -> 5.5 MiB (bf16) ~ L2-resident.
// Fallback to f32 gather (same partitioning) if ws_size < 44 MiB.

#define NUM_IN  45056
#define B_BATCH 16384
#define K_ACT   32
#define N_OUT   512
#define ROWS_PB 16
#define NSLICE  8
#define SLICE_C (N_OUT / NSLICE)   // 64 cols per slice

// ---------- W (f32) -> bf16 (RNE), grid-stride, float4-wide ----------
__global__ __launch_bounds__(256) void w_to_bf16_kernel(
    const float* __restrict__ W, ushort* __restrict__ Wb, int n4)
{
    int i = blockIdx.x * 256 + threadIdx.x;
    const int stride = gridDim.x * 256;
    for (; i < n4; i += stride) {
        const uint4 u = reinterpret_cast<const uint4*>(W)[i];
        ushort4 o;
        o.x = (ushort)((u.x + 0x7fffu + ((u.x >> 16) & 1u)) >> 16);
        o.y = (ushort)((u.y + 0x7fffu + ((u.y >> 16) & 1u)) >> 16);
        o.z = (ushort)((u.z + 0x7fffu + ((u.z >> 16) & 1u)) >> 16);
        o.w = (ushort)((u.w + 0x7fffu + ((u.w >> 16) & 1u)) >> 16);
        reinterpret_cast<ushort4*>(Wb)[i] = o;
    }
}

// ---------- gather, bf16 weights ----------
// Block: 16 batch rows x one 64-col slice. 128 threads: (r = t>>3, c = t&7),
// thread owns 8 cols. Per gather: one uint4 (8 bf16) load.
__global__ __launch_bounds__(128) void ft_gather_bf16(
    const int*   __restrict__ idx,
    const float* __restrict__ val,
    const ushort* __restrict__ Wb,
    const float* __restrict__ bias,
    float*       __restrict__ out)
{
    const int bid = blockIdx.x;
    const int s   = bid & (NSLICE - 1);   // slice -> XCD (round-robin dispatch)
    const int g   = bid >> 3;
    const int t   = threadIdx.x;
    const int r   = t >> 3;               // 0..15
    const int c   = t & 7;                // 0..7
    const int row0 = g * ROWS_PB;
    const int colbase = s * SLICE_C + c * 8;

    __shared__ int   s_idx[ROWS_PB][K_ACT + 1];  // +1 pad: conflict-free reads
    __shared__ float s_val[ROWS_PB][K_ACT + 1];
    {
        const int*   gi = idx + row0 * K_ACT;
        const float* gv = val + row0 * K_ACT;
        #pragma unroll
        for (int j = 0; j < (ROWS_PB * K_ACT) / 128; ++j) {
            const int e = t + j * 128;            // 0..511
            s_idx[e >> 5][e & 31] = gi[e];
            s_val[e >> 5][e & 31] = gv[e];
        }
    }
    __syncthreads();

    float acc[8];
    {
        const float4 b0 = *reinterpret_cast<const float4*>(bias + colbase);
        const float4 b1 = *reinterpret_cast<const float4*>(bias + colbase + 4);
        acc[0] = b0.x; acc[1] = b0.y; acc[2] = b0.z; acc[3] = b0.w;
        acc[4] = b1.x; acc[5] = b1.y; acc[6] = b1.z; acc[7] = b1.w;
    }

    #pragma unroll
    for (int k0 = 0; k0 < K_ACT; k0 += 4) {
        uint4 w[4];
        float v[4];
        #pragma unroll
        for (int j = 0; j < 4; ++j) {
            const int row = s_idx[r][k0 + j];
            v[j] = s_val[r][k0 + j];
            w[j] = *reinterpret_cast<const uint4*>(
                       Wb + (size_t)row * N_OUT + colbase);
        }
        #pragma unroll
        for (int j = 0; j < 4; ++j) {
            const float vj = v[j];
            acc[0] += vj * __builtin_bit_cast(float, w[j].x << 16);
            acc[1] += vj * __builtin_bit_cast(float, w[j].x & 0xffff0000u);
            acc[2] += vj * __builtin_bit_cast(float, w[j].y << 16);
            acc[3] += vj * __builtin_bit_cast(float, w[j].y & 0xffff0000u);
            acc[4] += vj * __builtin_bit_cast(float, w[j].z << 16);
            acc[5] += vj * __builtin_bit_cast(float, w[j].z & 0xffff0000u);
            acc[6] += vj * __builtin_bit_cast(float, w[j].w << 16);
            acc[7] += vj * __builtin_bit_cast(float, w[j].w & 0xffff0000u);
        }
    }

    float* o = out + (size_t)(row0 + r) * N_OUT + colbase;
    *reinterpret_cast<float4*>(o)     = make_float4(acc[0], acc[1], acc[2], acc[3]);
    *reinterpret_cast<float4*>(o + 4) = make_float4(acc[4], acc[5], acc[6], acc[7]);
}

// ---------- gather, f32 weights (fallback if ws too small) ----------
__global__ __launch_bounds__(128) void ft_gather_f32(
    const int*   __restrict__ idx,
    const float* __restrict__ val,
    const float* __restrict__ W,
    const float* __restrict__ bias,
    float*       __restrict__ out)
{
    const int bid = blockIdx.x;
    const int s   = bid & (NSLICE - 1);
    const int g   = bid >> 3;
    const int t   = threadIdx.x;
    const int r   = t >> 3;
    const int c   = t & 7;
    const int row0 = g * ROWS_PB;
    const int colbase = s * SLICE_C + c * 8;

    __shared__ int   s_idx[ROWS_PB][K_ACT + 1];
    __shared__ float s_val[ROWS_PB][K_ACT + 1];
    {
        const int*   gi = idx + row0 * K_ACT;
        const float* gv = val + row0 * K_ACT;
        #pragma unroll
        for (int j = 0; j < (ROWS_PB * K_ACT) / 128; ++j) {
            const int e = t + j * 128;
            s_idx[e >> 5][e & 31] = gi[e];
            s_val[e >> 5][e & 31] = gv[e];
        }
    }
    __syncthreads();

    float acc[8];
    {
        const float4 b0 = *reinterpret_cast<const float4*>(bias + colbase);
        const float4 b1 = *reinterpret_cast<const float4*>(bias + colbase + 4);
        acc[0] = b0.x; acc[1] = b0.y; acc[2] = b0.z; acc[3] = b0.w;
        acc[4] = b1.x; acc[5] = b1.y; acc[6] = b1.z; acc[7] = b1.w;
    }

    #pragma unroll
    for (int k0 = 0; k0 < K_ACT; k0 += 2) {
        float4 w[4];
        float  v[2];
        #pragma unroll
        for (int j = 0; j < 2; ++j) {
            const int row = s_idx[r][k0 + j];
            v[j] = s_val[r][k0 + j];
            const float* p = W + (size_t)row * N_OUT + colbase;
            w[2*j]   = *reinterpret_cast<const float4*>(p);
            w[2*j+1] = *reinterpret_cast<const float4*>(p + 4);
        }
        #pragma unroll
        for (int j = 0; j < 2; ++j) {
            const float vj = v[j];
            acc[0] += vj * w[2*j].x;   acc[1] += vj * w[2*j].y;
            acc[2] += vj * w[2*j].z;   acc[3] += vj * w[2*j].w;
            acc[4] += vj * w[2*j+1].x; acc[5] += vj * w[2*j+1].y;
            acc[6] += vj * w[2*j+1].z; acc[7] += vj * w[2*j+1].w;
        }
    }

    float* o = out + (size_t)(row0 + r) * N_OUT + colbase;
    *reinterpret_cast<float4*>(o)     = make_float4(acc[0], acc[1], acc[2], acc[3]);
    *reinterpret_cast<float4*>(o + 4) = make_float4(acc[4], acc[5], acc[6], acc[7]);
}

extern "C" void kernel_launch(void* const* d_in, const int* in_sizes, int n_in,
                              void* d_out, int out_size, void* d_ws, size_t ws_size,
                              hipStream_t stream) {
    const int*   idx  = (const int*)  d_in[0];
    const float* val  = (const float*)d_in[1];
    const float* W    = (const float*)d_in[2];
    const float* bias = (const float*)d_in[3];
    float*       out  = (float*)d_out;

    const int nblocks = (B_BATCH / ROWS_PB) * NSLICE;   // 8192
    const size_t wb_bytes = (size_t)NUM_IN * N_OUT * sizeof(ushort);

    if (ws_size >= wb_bytes) {
        ushort* Wb = (ushort*)d_ws;
        w_to_bf16_kernel<<<2048, 256, 0, stream>>>(W, Wb, NUM_IN * N_OUT / 4);
        ft_gather_bf16<<<nblocks, 128, 0, stream>>>(idx, val, Wb, bias, out);
    } else {
        ft_gather_f32<<<nblocks, 128, 0, stream>>>(idx, val, W, bias, out);
    }
}